// Round 1
// baseline (637.527 us; speedup 1.0000x reference)
//
#include <hip/hip_runtime.h>
#include <math.h>

#define BB 32
#define CC 768
#define HWN 1024
#define DD 384
#define KK 64
#define EPSI 20.0f            // 1/eps
#define NORMC (-6.9920964f)   // -log(1088)
#define NITERS 10

__device__ __forceinline__ float wave_sum(float v){
  #pragma unroll
  for (int off = 32; off; off >>= 1) v += __shfl_xor(v, off, 64);
  return v;
}
__device__ __forceinline__ float wave_max(float v){
  #pragma unroll
  for (int off = 32; off; off >>= 1) v = fmaxf(v, __shfl_xor(v, off, 64));
  return v;
}

// ---------------- K0: normalize codebook rows v[64][384] -> clusters ----------------
__global__ __launch_bounds__(256) void k0_clusters(const float* __restrict__ vin,
                                                   float* __restrict__ clus){
  int w = threadIdx.x >> 6, l = threadIdx.x & 63;
  int k = blockIdx.x * 4 + w;               // 16 blocks * 4 waves = 64 rows
  float s = 0.f;
  #pragma unroll
  for (int i = 0; i < 6; i++){ float x = vin[k*DD + l + 64*i]; s += x*x; }
  s = wave_sum(s);
  float scale = 1.f / fmaxf(sqrtf(s), 1e-12f);
  #pragma unroll
  for (int i = 0; i < 6; i++) clus[k*DD + l + 64*i] = vin[k*DD + l + 64*i] * scale;
}

// ---------------- K1: proj GEMM  Y_b = W[384,768] @ X_b[768,1024], +bias,
//                  write x_proj[b][n][d] via LDS transpose ----------------
__global__ __launch_bounds__(256) void k1_proj(const float* __restrict__ x,
                                               const float* __restrict__ w,
                                               const float* __restrict__ bias,
                                               float* __restrict__ xp){
  __shared__ float As[16][68];   // [kk][m(d)]  stride 68 -> 16B aligned float4 reads
  __shared__ float Bs[16][64];   // [kk][n]
  __shared__ float T [64][68];   // transpose staging [n][d]
  int b  = blockIdx.z;
  int d0 = blockIdx.y * 64;
  int n0 = blockIdx.x * 64;
  const float* X = x + (size_t)b * CC * HWN;
  int tid = threadIdx.x;
  int ty = tid >> 4, tx = tid & 15;
  float acc[4][4] = {};
  for (int k0 = 0; k0 < CC; k0 += 16){
    { // A: W[d0+m][k0 + q*4 + i] -> As[q*4+i][m]
      int m = tid >> 2, q = tid & 3;
      const float4 a4 = *(const float4*)&w[(size_t)(d0+m)*CC + k0 + q*4];
      As[q*4+0][m] = a4.x; As[q*4+1][m] = a4.y; As[q*4+2][m] = a4.z; As[q*4+3][m] = a4.w;
    }
    { // B: X[(k0+r)][n0 + cn .. +3] -> Bs[r][cn]
      int r = tid >> 4, cn = (tid & 15) * 4;
      *(float4*)&Bs[r][cn] = *(const float4*)&X[(size_t)(k0+r)*HWN + n0 + cn];
    }
    __syncthreads();
    #pragma unroll
    for (int kk = 0; kk < 16; kk++){
      const float4 a4 = *(const float4*)&As[kk][ty*4];
      const float4 b4 = *(const float4*)&Bs[kk][tx*4];
      const float av[4] = {a4.x, a4.y, a4.z, a4.w};
      const float bv[4] = {b4.x, b4.y, b4.z, b4.w};
      #pragma unroll
      for (int i = 0; i < 4; i++)
        #pragma unroll
        for (int j = 0; j < 4; j++)
          acc[i][j] = fmaf(av[i], bv[j], acc[i][j]);
    }
    __syncthreads();
  }
  // epilogue: add bias, transpose to [n][d], store coalesced
  float bv[4];
  #pragma unroll
  for (int i = 0; i < 4; i++) bv[i] = bias[d0 + ty*4 + i];
  #pragma unroll
  for (int i = 0; i < 4; i++)
    #pragma unroll
    for (int j = 0; j < 4; j++)
      T[tx*4 + j][ty*4 + i] = acc[i][j] + bv[i];
  __syncthreads();
  {
    int nn = tid >> 2, q = tid & 3;
    float* orow = xp + (size_t)(b*HWN + n0 + nn) * DD + d0;
    #pragma unroll
    for (int c = 0; c < 4; c++){
      int doff = q*4 + c*16;
      float4 o = *(const float4*)&T[nn][doff];
      *(float4*)&orow[doff] = o;
    }
  }
}

// ---------------- K2: per-token 1/max(||x_proj||,1e-12) ----------------
__global__ __launch_bounds__(256) void k2_rnorm(const float* __restrict__ xp,
                                                float* __restrict__ rn){
  int w = threadIdx.x >> 6, l = threadIdx.x & 63;
  int t = blockIdx.x * 4 + w;               // 0..32767
  const float* row = xp + (size_t)t * DD;
  float s = 0.f;
  #pragma unroll
  for (int i = 0; i < 6; i++){ float xv = row[l + 64*i]; s += xv*xv; }
  s = wave_sum(s);
  if (l == 0) rn[t] = 1.f / fmaxf(sqrtf(s), 1e-12f);
}

// ---------------- K3: Z[b][k][n] = (clusters @ x_proj_b^T) * rnorm[n] / eps ----------
__global__ __launch_bounds__(256) void k3_scores(const float* __restrict__ clus,
                                                 const float* __restrict__ xp,
                                                 const float* __restrict__ rn,
                                                 float* __restrict__ Z){
  __shared__ float As[16][68];  // [dd][k]
  __shared__ float Bs[16][68];  // [dd][n]
  int b = blockIdx.y, n0 = blockIdx.x * 64;
  const float* xpb = xp + (size_t)b * HWN * DD;
  int tid = threadIdx.x, ty = tid >> 4, tx = tid & 15;
  float acc[4][4] = {};
  for (int d0 = 0; d0 < DD; d0 += 16){
    { // A: clusters[k][d0+q*4 ..] -> As[q*4+i][k]
      int k = tid >> 2, q = tid & 3;
      const float4 a4 = *(const float4*)&clus[(size_t)k*DD + d0 + q*4];
      As[q*4+0][k] = a4.x; As[q*4+1][k] = a4.y; As[q*4+2][k] = a4.z; As[q*4+3][k] = a4.w;
    }
    { // B: xp[n0+nn][d0+q*4 ..] -> Bs[q*4+i][nn]
      int nn = tid >> 2, q = tid & 3;
      const float4 x4 = *(const float4*)&xpb[(size_t)(n0+nn)*DD + d0 + q*4];
      Bs[q*4+0][nn] = x4.x; Bs[q*4+1][nn] = x4.y; Bs[q*4+2][nn] = x4.z; Bs[q*4+3][nn] = x4.w;
    }
    __syncthreads();
    #pragma unroll
    for (int kk = 0; kk < 16; kk++){
      const float4 a4 = *(const float4*)&As[kk][ty*4];
      const float4 b4 = *(const float4*)&Bs[kk][tx*4];
      const float av[4] = {a4.x, a4.y, a4.z, a4.w};
      const float bv[4] = {b4.x, b4.y, b4.z, b4.w};
      #pragma unroll
      for (int i = 0; i < 4; i++)
        #pragma unroll
        for (int j = 0; j < 4; j++)
          acc[i][j] = fmaf(av[i], bv[j], acc[i][j]);
    }
    __syncthreads();
  }
  const float* rnb = rn + (size_t)b * HWN;
  #pragma unroll
  for (int i = 0; i < 4; i++){
    int k = ty*4 + i;
    int n = n0 + tx*4;
    float4 o;
    o.x = acc[i][0] * rnb[n+0] * EPSI;
    o.y = acc[i][1] * rnb[n+1] * EPSI;
    o.z = acc[i][2] * rnb[n+2] * EPSI;
    o.w = acc[i][3] * rnb[n+3] * EPSI;
    *(float4*)&Z[((size_t)b*KK + k)*HWN + n] = o;
  }
}

// ---------------- K4: Sinkhorn, one block (1024 thr) per batch ----------------
__global__ __launch_bounds__(1024) void k4_sinkhorn(const float* __restrict__ Z,
                                                    float* __restrict__ U,
                                                    float* __restrict__ V){
  __shared__ float v_lds[1024];
  __shared__ float u_lds[64];
  __shared__ float rmax[64];
  __shared__ float wmax[16];
  int b = blockIdx.x;
  const float* Zb = Z + (size_t)b * KK * HWN;
  int t = threadIdx.x, w = t >> 6, l = t & 63;
  // col max (thread t owns column t)
  float cmax = -INFINITY;
  #pragma unroll 8
  for (int m = 0; m < 64; m++) cmax = fmaxf(cmax, Zb[m*HWN + t]);
  // row max (wave w handles rows 4w..4w+3)
  #pragma unroll
  for (int rr = 0; rr < 4; rr++){
    int r = w*4 + rr;
    float mx = -INFINITY;
    #pragma unroll
    for (int s = 0; s < 16; s++) mx = fmaxf(mx, Zb[r*HWN + s*64 + l]);
    mx = wave_max(mx);
    if (l == 0) rmax[r] = mx;
  }
  v_lds[t] = 0.f;
  __syncthreads();
  float vmax = 0.f;
  for (int it = 0; it < NITERS; it++){
    // u-phase: u[r] = norm - lse_n(Z[r,:] + v)
    #pragma unroll
    for (int rr = 0; rr < 4; rr++){
      int r = w*4 + rr;
      float shift = rmax[r] + vmax;
      float s = 0.f;
      #pragma unroll
      for (int ss = 0; ss < 16; ss++){
        int n = ss*64 + l;
        s += __expf(Zb[r*HWN + n] + v_lds[n] - shift);
      }
      s = wave_sum(s);
      if (l == 0) u_lds[r] = NORMC - (shift + __logf(s));
    }
    __syncthreads();
    // v-phase: v[t] = norm - lse_m(Z[:,t] + u)
    float umax = -INFINITY;
    #pragma unroll 8
    for (int m = 0; m < 64; m++) umax = fmaxf(umax, u_lds[m]);
    float shift = cmax + umax;
    float s = 0.f;
    #pragma unroll 8
    for (int m = 0; m < 64; m++) s += __expf(Zb[m*HWN + t] + u_lds[m] - shift);
    float v_t = NORMC - (shift + __logf(s));
    v_lds[t] = v_t;
    float wm = wave_max(v_t);
    if (l == 0) wmax[w] = wm;
    __syncthreads();
    vmax = wmax[0];
    #pragma unroll
    for (int i = 1; i < 16; i++) vmax = fmaxf(vmax, wmax[i]);
  }
  if (t < 64) U[b*KK + t] = u_lds[t];
  V[b*HWN + t] = v_lds[t];
}

// ---------------- K5: v_tilde[b][k][d] = sum_n exp(Z+u+v-norm) * xp[n][d]*rnorm[n] ----
__global__ __launch_bounds__(256) void k5_vtilde(const float* __restrict__ Z,
                                                 const float* __restrict__ U,
                                                 const float* __restrict__ V,
                                                 const float* __restrict__ xp,
                                                 const float* __restrict__ rn,
                                                 float* __restrict__ out){
  __shared__ float As[16][68];   // [nn][k]   A = weights^T (generated on the fly)
  __shared__ float Bs[16][64];   // [nn][d]
  int b = blockIdx.y;
  int d0 = blockIdx.x * 64;
  const float* Zb  = Z + (size_t)b * KK * HWN;
  const float* ub  = U + (size_t)b * KK;
  const float* vb  = V + (size_t)b * HWN;
  const float* xpb = xp + (size_t)b * HWN * DD;
  const float* rnb = rn + (size_t)b * HWN;
  int tid = threadIdx.x, ty = tid >> 4, tx = tid & 15;
  float acc[4][4] = {};
  for (int n0 = 0; n0 < HWN; n0 += 16){
    { // A-gen: As[q*4+i][m] = exp(Z[m][n0+q*4+i] + u[m] + v[..] - norm)
      int m = tid >> 2, q = tid & 3;
      float um = ub[m];
      const float4 z4 = *(const float4*)&Zb[(size_t)m*HWN + n0 + q*4];
      const float4 v4 = *(const float4*)&vb[n0 + q*4];
      As[q*4+0][m] = __expf(z4.x + um + v4.x - NORMC);
      As[q*4+1][m] = __expf(z4.y + um + v4.y - NORMC);
      As[q*4+2][m] = __expf(z4.z + um + v4.z - NORMC);
      As[q*4+3][m] = __expf(z4.w + um + v4.w - NORMC);
    }
    { // B: Bs[r][cd..] = xp[n0+r][d0+cd..] * rnorm[n0+r]
      int r = tid >> 4, cd = (tid & 15) * 4;
      float sc = rnb[n0 + r];
      float4 xv = *(const float4*)&xpb[(size_t)(n0+r)*DD + d0 + cd];
      xv.x *= sc; xv.y *= sc; xv.z *= sc; xv.w *= sc;
      *(float4*)&Bs[r][cd] = xv;
    }
    __syncthreads();
    #pragma unroll
    for (int kk = 0; kk < 16; kk++){
      const float4 a4 = *(const float4*)&As[kk][ty*4];
      const float4 b4 = *(const float4*)&Bs[kk][tx*4];
      const float av[4] = {a4.x, a4.y, a4.z, a4.w};
      const float bv[4] = {b4.x, b4.y, b4.z, b4.w};
      #pragma unroll
      for (int i = 0; i < 4; i++)
        #pragma unroll
        for (int j = 0; j < 4; j++)
          acc[i][j] = fmaf(av[i], bv[j], acc[i][j]);
    }
    __syncthreads();
  }
  #pragma unroll
  for (int i = 0; i < 4; i++){
    int k = ty*4 + i;
    float4 o; o.x = acc[i][0]; o.y = acc[i][1]; o.z = acc[i][2]; o.w = acc[i][3];
    *(float4*)&out[((size_t)b*KK + k)*DD + d0 + tx*4] = o;
  }
}

extern "C" void kernel_launch(void* const* d_in, const int* in_sizes, int n_in,
                              void* d_out, int out_size, void* d_ws, size_t ws_size,
                              hipStream_t stream) {
  const float* x      = (const float*)d_in[0];   // [32,768,32,32]
  const float* conv_w = (const float*)d_in[1];   // [384,768]
  const float* conv_b = (const float*)d_in[2];   // [384]
  const float* vcode  = (const float*)d_in[3];   // [64,384]
  float* out = (float*)d_out;
  float* vt_out = out;                 // [32,64,384]  = 786432
  float* xp_out = out + 786432;        // [32,1024,384]

  float* ws   = (float*)d_ws;
  float* clus = ws;                    // 24576
  float* Zbuf = clus + 24576;          // 2097152
  float* Ubuf = Zbuf + 2097152;        // 2048
  float* Vbuf = Ubuf + 2048;           // 32768
  float* Rn   = Vbuf + 32768;          // 32768   (total ~8.75 MB)

  k0_clusters<<<16, 256, 0, stream>>>(vcode, clus);
  k1_proj<<<dim3(16, 6, 32), 256, 0, stream>>>(x, conv_w, conv_b, xp_out);
  k2_rnorm<<<8192, 256, 0, stream>>>(xp_out, Rn);
  k3_scores<<<dim3(16, 32), 256, 0, stream>>>(clus, xp_out, Rn, Zbuf);
  k4_sinkhorn<<<32, 1024, 0, stream>>>(Zbuf, Ubuf, Vbuf);
  k5_vtilde<<<dim3(6, 32), 256, 0, stream>>>(Zbuf, Ubuf, Vbuf, xp_out, Rn, vt_out);
}

// Round 2
// 434.403 us; speedup vs baseline: 1.4676x; 1.4676x over previous
//
#include <hip/hip_runtime.h>
#include <math.h>

#define BB 32
#define CC 768
#define HWN 1024
#define DD 384
#define KK 64
#define EPSI 20.0f            // 1/eps
#define NORMC (-6.9920964f)   // -log(1088)
#define NITERS 10

typedef __bf16 bf16;
typedef bf16 bf16x8 __attribute__((ext_vector_type(8)));
typedef bf16 bf16x4 __attribute__((ext_vector_type(4)));
typedef float f32x4 __attribute__((ext_vector_type(4)));

__device__ __forceinline__ float wave_sum(float v){
  #pragma unroll
  for (int off = 32; off; off >>= 1) v += __shfl_xor(v, off, 64);
  return v;
}
__device__ __forceinline__ float wave_max(float v){
  #pragma unroll
  for (int off = 32; off; off >>= 1) v = fmaxf(v, __shfl_xor(v, off, 64));
  return v;
}

__device__ __forceinline__ void async16(const bf16* g, bf16* l){
  __builtin_amdgcn_global_load_lds((const __attribute__((address_space(1))) unsigned int*)g,
                                   (__attribute__((address_space(3))) unsigned int*)l,
                                   16, 0, 0);
}

// ---------------- K0: normalize codebook rows v[64][384] -> clusters ----------------
__global__ __launch_bounds__(256) void k0_clusters(const float* __restrict__ vin,
                                                   float* __restrict__ clus){
  int w = threadIdx.x >> 6, l = threadIdx.x & 63;
  int k = blockIdx.x * 4 + w;               // 16 blocks * 4 waves = 64 rows
  float s = 0.f;
  #pragma unroll
  for (int i = 0; i < 6; i++){ float x = vin[k*DD + l + 64*i]; s += x*x; }
  s = wave_sum(s);
  float scale = 1.f / fmaxf(sqrtf(s), 1e-12f);
  #pragma unroll
  for (int i = 0; i < 6; i++) clus[k*DD + l + 64*i] = vin[k*DD + l + 64*i] * scale;
}

// ---------------- KW: convert conv_w fp32[384][768] -> bf16 ----------------
__global__ __launch_bounds__(256) void k_wconv(const float* __restrict__ w,
                                               bf16* __restrict__ wb){
  int i = (blockIdx.x * 256 + threadIdx.x) * 4;
  float4 v = *(const float4*)&w[i];
  bf16x4 o;
  o[0] = (bf16)v.x; o[1] = (bf16)v.y; o[2] = (bf16)v.z; o[3] = (bf16)v.w;
  *(bf16x4*)&wb[i] = o;
}

// ---------------- KXT: X[b][768][1024] fp32 -> Xt[b][1024][768] bf16 (transpose) -----
__global__ __launch_bounds__(256) void k_xt(const float* __restrict__ x,
                                            bf16* __restrict__ xt){
  __shared__ float S[64][68];
  int b  = blockIdx.z;
  int k0 = blockIdx.y * 64;   // channel dim
  int n0 = blockIdx.x * 64;   // spatial dim
  const float* X = x + (size_t)b * CC * HWN;
  int t = threadIdx.x;
  int rr = t >> 4, cc = (t & 15) * 4;
  #pragma unroll
  for (int it = 0; it < 4; it++){
    float4 v = *(const float4*)&X[(size_t)(k0 + rr + it*16)*HWN + n0 + cc];
    *(float4*)&S[rr + it*16][cc] = v;
  }
  __syncthreads();
  int n = t >> 2, kc = t & 3;
  bf16* orow = xt + (size_t)b * HWN * CC + (size_t)(n0 + n) * CC + k0;
  #pragma unroll
  for (int half = 0; half < 2; half++){
    int kb = half*32 + kc*8;
    bf16x8 o;
    #pragma unroll
    for (int jj = 0; jj < 8; jj++){
      int j = (jj + kc) & 7;   // rotate read order to dodge bank conflicts
      o[j] = (bf16)S[kb + j][n];
    }
    *(bf16x8*)&orow[kb] = o;
  }
}

// ---------------- K1: MFMA GEMM  xp[b][n][m] = sum_k Xt[b][n][k] * Wb[m][k] + bias[m]
// 128x128 tile per block, 4 waves of 64x64, BK=32, global_load_lds staging.
__global__ __launch_bounds__(256) void k_gemm(const bf16* __restrict__ Wb,
                                              const bf16* __restrict__ Xt,
                                              const float* __restrict__ bias,
                                              float* __restrict__ xp){
  __shared__ bf16 Wl[4][128][8];   // [kquad][row(m)][8 bf16]  8 KB
  __shared__ bf16 Xl[4][128][8];   // [kquad][row(n)][8 bf16]  8 KB
  int b  = blockIdx.z;
  int m0 = blockIdx.y * 128;
  int n0 = blockIdx.x * 128;
  int t = threadIdx.x, wv = t >> 6, l = t & 63;
  int l15 = l & 15, quad = l >> 4;
  int wn = wv >> 1, wm = wv & 1;
  const bf16* Xb = Xt + (size_t)b * HWN * CC;

  // staging decomposition: chunk c = issue*256 + t; kq = c>>7, row = c&127
  int kqA = wv >> 1;          // issue 1 adds 2
  int rb  = (wv & 1) * 64;    // lane row = rb + l
  const bf16* gW0 = Wb + (size_t)(m0 + rb + l) * CC + kqA * 8;
  const bf16* gX0 = Xb + (size_t)(n0 + rb + l) * CC + kqA * 8;
  bf16* lW0 = &Wl[0][0][0] + wv * 512;   // bytes: wv*1024
  bf16* lX0 = &Xl[0][0][0] + wv * 512;

  f32x4 acc[4][4];
  const f32x4 zero = {0.f, 0.f, 0.f, 0.f};
  #pragma unroll
  for (int i = 0; i < 4; i++)
    #pragma unroll
    for (int j = 0; j < 4; j++) acc[i][j] = zero;

  for (int k0 = 0; k0 < CC; k0 += 32){
    async16(gW0 + k0,      lW0);
    async16(gW0 + k0 + 16, lW0 + 2048);
    async16(gX0 + k0,      lX0);
    async16(gX0 + k0 + 16, lX0 + 2048);
    __syncthreads();
    bf16x8 xf[4], wf[4];
    #pragma unroll
    for (int i = 0; i < 4; i++)
      xf[i] = *(const bf16x8*)&Xl[quad][wn*64 + i*16 + l15][0];
    #pragma unroll
    for (int j = 0; j < 4; j++)
      wf[j] = *(const bf16x8*)&Wl[quad][wm*64 + j*16 + l15][0];
    #pragma unroll
    for (int i = 0; i < 4; i++)
      #pragma unroll
      for (int j = 0; j < 4; j++)
        acc[i][j] = __builtin_amdgcn_mfma_f32_16x16x32_bf16(xf[i], wf[j], acc[i][j], 0, 0, 0);
    __syncthreads();
  }

  float bb[4];
  #pragma unroll
  for (int j = 0; j < 4; j++) bb[j] = bias[m0 + wm*64 + j*16 + l15];
  #pragma unroll
  for (int i = 0; i < 4; i++){
    int nb = n0 + wn*64 + i*16 + quad*4;
    #pragma unroll
    for (int r = 0; r < 4; r++){
      float* orow = xp + ((size_t)b * HWN + nb + r) * DD;
      #pragma unroll
      for (int j = 0; j < 4; j++){
        int m = m0 + wm*64 + j*16 + l15;
        orow[m] = acc[i][j][r] + bb[j];
      }
    }
  }
}

// ---------------- K2: per-token 1/max(||x_proj||,1e-12) ----------------
__global__ __launch_bounds__(256) void k2_rnorm(const float* __restrict__ xp,
                                                float* __restrict__ rn){
  int w = threadIdx.x >> 6, l = threadIdx.x & 63;
  int t = blockIdx.x * 4 + w;               // 0..32767
  const float* row = xp + (size_t)t * DD;
  float s = 0.f;
  #pragma unroll
  for (int i = 0; i < 6; i++){ float xv = row[l + 64*i]; s += xv*xv; }
  s = wave_sum(s);
  if (l == 0) rn[t] = 1.f / fmaxf(sqrtf(s), 1e-12f);
}

// ---------------- K3: Z[b][k][n] = (clusters @ x_proj_b^T) * rnorm[n] / eps ----------
__global__ __launch_bounds__(256) void k3_scores(const float* __restrict__ clus,
                                                 const float* __restrict__ xp,
                                                 const float* __restrict__ rn,
                                                 float* __restrict__ Z){
  __shared__ float As[16][68];  // [dd][k]
  __shared__ float Bs[16][68];  // [dd][n]
  int b = blockIdx.y, n0 = blockIdx.x * 64;
  const float* xpb = xp + (size_t)b * HWN * DD;
  int tid = threadIdx.x, ty = tid >> 4, tx = tid & 15;
  float acc[4][4] = {};
  for (int d0 = 0; d0 < DD; d0 += 16){
    { // A: clusters[k][d0+q*4 ..] -> As[q*4+i][k]
      int k = tid >> 2, q = tid & 3;
      const float4 a4 = *(const float4*)&clus[(size_t)k*DD + d0 + q*4];
      As[q*4+0][k] = a4.x; As[q*4+1][k] = a4.y; As[q*4+2][k] = a4.z; As[q*4+3][k] = a4.w;
    }
    { // B: xp[n0+nn][d0+q*4 ..] -> Bs[q*4+i][nn]
      int nn = tid >> 2, q = tid & 3;
      const float4 x4 = *(const float4*)&xpb[(size_t)(n0+nn)*DD + d0 + q*4];
      Bs[q*4+0][nn] = x4.x; Bs[q*4+1][nn] = x4.y; Bs[q*4+2][nn] = x4.z; Bs[q*4+3][nn] = x4.w;
    }
    __syncthreads();
    #pragma unroll
    for (int kk = 0; kk < 16; kk++){
      const float4 a4 = *(const float4*)&As[kk][ty*4];
      const float4 b4 = *(const float4*)&Bs[kk][tx*4];
      const float av[4] = {a4.x, a4.y, a4.z, a4.w};
      const float bv[4] = {b4.x, b4.y, b4.z, b4.w};
      #pragma unroll
      for (int i = 0; i < 4; i++)
        #pragma unroll
        for (int j = 0; j < 4; j++)
          acc[i][j] = fmaf(av[i], bv[j], acc[i][j]);
    }
    __syncthreads();
  }
  const float* rnb = rn + (size_t)b * HWN;
  #pragma unroll
  for (int i = 0; i < 4; i++){
    int k = ty*4 + i;
    int n = n0 + tx*4;
    float4 o;
    o.x = acc[i][0] * rnb[n+0] * EPSI;
    o.y = acc[i][1] * rnb[n+1] * EPSI;
    o.z = acc[i][2] * rnb[n+2] * EPSI;
    o.w = acc[i][3] * rnb[n+3] * EPSI;
    *(float4*)&Z[((size_t)b*KK + k)*HWN + n] = o;
  }
}

// ---------------- K4: Sinkhorn, one block (1024 thr) per batch ----------------
__global__ __launch_bounds__(1024) void k4_sinkhorn(const float* __restrict__ Z,
                                                    float* __restrict__ U,
                                                    float* __restrict__ V){
  __shared__ float v_lds[1024];
  __shared__ float u_lds[64];
  __shared__ float rmax[64];
  __shared__ float wmax[16];
  int b = blockIdx.x;
  const float* Zb = Z + (size_t)b * KK * HWN;
  int t = threadIdx.x, w = t >> 6, l = t & 63;
  float cmax = -INFINITY;
  #pragma unroll 8
  for (int m = 0; m < 64; m++) cmax = fmaxf(cmax, Zb[m*HWN + t]);
  #pragma unroll
  for (int rr = 0; rr < 4; rr++){
    int r = w*4 + rr;
    float mx = -INFINITY;
    #pragma unroll
    for (int s = 0; s < 16; s++) mx = fmaxf(mx, Zb[r*HWN + s*64 + l]);
    mx = wave_max(mx);
    if (l == 0) rmax[r] = mx;
  }
  v_lds[t] = 0.f;
  __syncthreads();
  float vmax = 0.f;
  for (int it = 0; it < NITERS; it++){
    #pragma unroll
    for (int rr = 0; rr < 4; rr++){
      int r = w*4 + rr;
      float shift = rmax[r] + vmax;
      float s = 0.f;
      #pragma unroll
      for (int ss = 0; ss < 16; ss++){
        int n = ss*64 + l;
        s += __expf(Zb[r*HWN + n] + v_lds[n] - shift);
      }
      s = wave_sum(s);
      if (l == 0) u_lds[r] = NORMC - (shift + __logf(s));
    }
    __syncthreads();
    float umax = -INFINITY;
    #pragma unroll 8
    for (int m = 0; m < 64; m++) umax = fmaxf(umax, u_lds[m]);
    float shift = cmax + umax;
    float s = 0.f;
    #pragma unroll 8
    for (int m = 0; m < 64; m++) s += __expf(Zb[m*HWN + t] + u_lds[m] - shift);
    float v_t = NORMC - (shift + __logf(s));
    v_lds[t] = v_t;
    float wm = wave_max(v_t);
    if (l == 0) wmax[w] = wm;
    __syncthreads();
    vmax = wmax[0];
    #pragma unroll
    for (int i = 1; i < 16; i++) vmax = fmaxf(vmax, wmax[i]);
  }
  if (t < 64) U[b*KK + t] = u_lds[t];
  V[b*HWN + t] = v_lds[t];
}

// ---------------- K5: v_tilde[b][k][d] = sum_n exp(Z+u+v-norm) * xp[n][d]*rnorm[n] ----
__global__ __launch_bounds__(256) void k5_vtilde(const float* __restrict__ Z,
                                                 const float* __restrict__ U,
                                                 const float* __restrict__ V,
                                                 const float* __restrict__ xp,
                                                 const float* __restrict__ rn,
                                                 float* __restrict__ out){
  __shared__ float As[16][68];   // [nn][k]   A = weights^T (generated on the fly)
  __shared__ float Bs[16][64];   // [nn][d]
  int b = blockIdx.y;
  int d0 = blockIdx.x * 64;
  const float* Zb  = Z + (size_t)b * KK * HWN;
  const float* ub  = U + (size_t)b * KK;
  const float* vb  = V + (size_t)b * HWN;
  const float* xpb = xp + (size_t)b * HWN * DD;
  const float* rnb = rn + (size_t)b * HWN;
  int tid = threadIdx.x, ty = tid >> 4, tx = tid & 15;
  float acc[4][4] = {};
  for (int n0 = 0; n0 < HWN; n0 += 16){
    {
      int m = tid >> 2, q = tid & 3;
      float um = ub[m];
      const float4 z4 = *(const float4*)&Zb[(size_t)m*HWN + n0 + q*4];
      const float4 v4 = *(const float4*)&vb[n0 + q*4];
      As[q*4+0][m] = __expf(z4.x + um + v4.x - NORMC);
      As[q*4+1][m] = __expf(z4.y + um + v4.y - NORMC);
      As[q*4+2][m] = __expf(z4.z + um + v4.z - NORMC);
      As[q*4+3][m] = __expf(z4.w + um + v4.w - NORMC);
    }
    {
      int r = tid >> 4, cd = (tid & 15) * 4;
      float sc = rnb[n0 + r];
      float4 xv = *(const float4*)&xpb[(size_t)(n0+r)*DD + d0 + cd];
      xv.x *= sc; xv.y *= sc; xv.z *= sc; xv.w *= sc;
      *(float4*)&Bs[r][cd] = xv;
    }
    __syncthreads();
    #pragma unroll
    for (int kk = 0; kk < 16; kk++){
      const float4 a4 = *(const float4*)&As[kk][ty*4];
      const float4 b4 = *(const float4*)&Bs[kk][tx*4];
      const float av[4] = {a4.x, a4.y, a4.z, a4.w};
      const float bv[4] = {b4.x, b4.y, b4.z, b4.w};
      #pragma unroll
      for (int i = 0; i < 4; i++)
        #pragma unroll
        for (int j = 0; j < 4; j++)
          acc[i][j] = fmaf(av[i], bv[j], acc[i][j]);
    }
    __syncthreads();
  }
  #pragma unroll
  for (int i = 0; i < 4; i++){
    int k = ty*4 + i;
    float4 o; o.x = acc[i][0]; o.y = acc[i][1]; o.z = acc[i][2]; o.w = acc[i][3];
    *(float4*)&out[((size_t)b*KK + k)*DD + d0 + tx*4] = o;
  }
}

extern "C" void kernel_launch(void* const* d_in, const int* in_sizes, int n_in,
                              void* d_out, int out_size, void* d_ws, size_t ws_size,
                              hipStream_t stream) {
  const float* x      = (const float*)d_in[0];   // [32,768,32,32]
  const float* conv_w = (const float*)d_in[1];   // [384,768]
  const float* conv_b = (const float*)d_in[2];   // [384]
  const float* vcode  = (const float*)d_in[3];   // [64,384]
  float* out = (float*)d_out;
  float* vt_out = out;                 // [32,64,384]  = 786432
  float* xp_out = out + 786432;        // [32,1024,384]

  bf16* Xt   = (bf16*)d_ws;                          // 25165824 elems (50.3 MB)
  bf16* Wb   = Xt + (size_t)BB * HWN * CC;           // 294912 elems (0.6 MB)
  float* clus = (float*)(Wb + (size_t)DD * CC);      // 24576
  float* Zbuf = clus + 24576;                        // 2097152
  float* Ubuf = Zbuf + 2097152;                      // 2048
  float* Vbuf = Ubuf + 2048;                         // 32768
  float* Rn   = Vbuf + 32768;                        // 32768  (total ~59.7 MB)

  k0_clusters<<<16, 256, 0, stream>>>(vcode, clus);
  k_wconv<<<288, 256, 0, stream>>>(conv_w, Wb);
  k_xt<<<dim3(16, 12, 32), 256, 0, stream>>>(x, Xt);
  k_gemm<<<dim3(8, 3, 32), 256, 0, stream>>>(Wb, Xt, conv_b, xp_out);
  k2_rnorm<<<8192, 256, 0, stream>>>(xp_out, Rn);
  k3_scores<<<dim3(16, 32), 256, 0, stream>>>(clus, xp_out, Rn, Zbuf);
  k4_sinkhorn<<<32, 1024, 0, stream>>>(Zbuf, Ubuf, Vbuf);
  k5_vtilde<<<dim3(6, 32), 256, 0, stream>>>(Zbuf, Ubuf, Vbuf, xp_out, Rn, vt_out);
}

// Round 3
// 425.413 us; speedup vs baseline: 1.4986x; 1.0211x over previous
//
#include <hip/hip_runtime.h>
#include <math.h>

#define BB 32
#define CC 768
#define HWN 1024
#define DD 384
#define KK 64
#define EPSI 20.0f            // 1/eps
#define NORMC (-6.9920964f)   // -log(1088)
#define NITERS 10

typedef __bf16 bf16;
typedef bf16 bf16x8 __attribute__((ext_vector_type(8)));
typedef bf16 bf16x4 __attribute__((ext_vector_type(4)));
typedef float f32x4 __attribute__((ext_vector_type(4)));

__device__ __forceinline__ float wave_sum(float v){
  #pragma unroll
  for (int off = 32; off; off >>= 1) v += __shfl_xor(v, off, 64);
  return v;
}
__device__ __forceinline__ float wave_max(float v){
  #pragma unroll
  for (int off = 32; off; off >>= 1) v = fmaxf(v, __shfl_xor(v, off, 64));
  return v;
}

__device__ __forceinline__ void async16(const bf16* g, bf16* l){
  __builtin_amdgcn_global_load_lds((const __attribute__((address_space(1))) unsigned int*)g,
                                   (__attribute__((address_space(3))) unsigned int*)l,
                                   16, 0, 0);
}

// Per-batch barrier: 8 blocks arrive on one counter slot (slot used once per launch).
// Release RMW flushes XCD L2 (writes visible at LLC); acquire RMW after spin
// invalidates local caches so partials read fresh. Co-residency guaranteed:
// 256 blocks x 256thr, ~35KB LDS -> >=4 blocks/CU capacity (1024 >= 256).
__device__ __forceinline__ void batch_barrier(unsigned* c){
  __syncthreads();   // drains vmcnt: all block's global stores are in L2
  if (threadIdx.x == 0){
    __hip_atomic_fetch_add(c, 1u, __ATOMIC_RELEASE, __HIP_MEMORY_SCOPE_AGENT);
    while (__hip_atomic_load(c, __ATOMIC_RELAXED, __HIP_MEMORY_SCOPE_AGENT) < 8u){
      __builtin_amdgcn_s_sleep(1);
    }
    __hip_atomic_fetch_add(c, 0u, __ATOMIC_ACQUIRE, __HIP_MEMORY_SCOPE_AGENT);
  }
  __syncthreads();
}

// ---------------- K_init: zero the barrier counters (ws is poisoned 0xAA) -----------
__global__ void k_init(unsigned* __restrict__ cnt){
  cnt[threadIdx.x] = 0u;   // 512 slots
}

// ---------------- K0: normalize codebook rows v[64][384] -> clusters ----------------
__global__ __launch_bounds__(256) void k0_clusters(const float* __restrict__ vin,
                                                   float* __restrict__ clus){
  int w = threadIdx.x >> 6, l = threadIdx.x & 63;
  int k = blockIdx.x * 4 + w;               // 16 blocks * 4 waves = 64 rows
  float s = 0.f;
  #pragma unroll
  for (int i = 0; i < 6; i++){ float x = vin[k*DD + l + 64*i]; s += x*x; }
  s = wave_sum(s);
  float scale = 1.f / fmaxf(sqrtf(s), 1e-12f);
  #pragma unroll
  for (int i = 0; i < 6; i++) clus[k*DD + l + 64*i] = vin[k*DD + l + 64*i] * scale;
}

// ---------------- KW: convert conv_w fp32[384][768] -> bf16 ----------------
__global__ __launch_bounds__(256) void k_wconv(const float* __restrict__ w,
                                               bf16* __restrict__ wb){
  int i = (blockIdx.x * 256 + threadIdx.x) * 4;
  float4 v = *(const float4*)&w[i];
  bf16x4 o;
  o[0] = (bf16)v.x; o[1] = (bf16)v.y; o[2] = (bf16)v.z; o[3] = (bf16)v.w;
  *(bf16x4*)&wb[i] = o;
}

// ---------------- KXT: X[b][768][1024] fp32 -> Xt[b][1024][768] bf16 (transpose) -----
__global__ __launch_bounds__(256) void k_xt(const float* __restrict__ x,
                                            bf16* __restrict__ xt){
  __shared__ float S[64][68];
  int b  = blockIdx.z;
  int k0 = blockIdx.y * 64;   // channel dim
  int n0 = blockIdx.x * 64;   // spatial dim
  const float* X = x + (size_t)b * CC * HWN;
  int t = threadIdx.x;
  int rr = t >> 4, cc = (t & 15) * 4;
  #pragma unroll
  for (int it = 0; it < 4; it++){
    float4 v = *(const float4*)&X[(size_t)(k0 + rr + it*16)*HWN + n0 + cc];
    *(float4*)&S[rr + it*16][cc] = v;
  }
  __syncthreads();
  int n = t >> 2, kc = t & 3;
  bf16* orow = xt + (size_t)b * HWN * CC + (size_t)(n0 + n) * CC + k0;
  #pragma unroll
  for (int half = 0; half < 2; half++){
    int kb = half*32 + kc*8;
    bf16x8 o;
    #pragma unroll
    for (int jj = 0; jj < 8; jj++){
      int j = (jj + kc) & 7;   // rotate read order to dodge bank conflicts
      o[j] = (bf16)S[kb + j][n];
    }
    *(bf16x8*)&orow[kb] = o;
  }
}

// ---------------- K1: MFMA GEMM  xp[b][n][m] = sum_k Xt[b][n][k] * Wb[m][k] + bias[m]
__global__ __launch_bounds__(256) void k_gemm(const bf16* __restrict__ Wb,
                                              const bf16* __restrict__ Xt,
                                              const float* __restrict__ bias,
                                              float* __restrict__ xp){
  __shared__ bf16 Wl[4][128][8];   // [kquad][row(m)][8 bf16]  8 KB
  __shared__ bf16 Xl[4][128][8];   // [kquad][row(n)][8 bf16]  8 KB
  int b  = blockIdx.z;
  int m0 = blockIdx.y * 128;
  int n0 = blockIdx.x * 128;
  int t = threadIdx.x, wv = t >> 6, l = t & 63;
  int l15 = l & 15, quad = l >> 4;
  int wn = wv >> 1, wm = wv & 1;
  const bf16* Xb = Xt + (size_t)b * HWN * CC;

  int kqA = wv >> 1;
  int rb  = (wv & 1) * 64;
  const bf16* gW0 = Wb + (size_t)(m0 + rb + l) * CC + kqA * 8;
  const bf16* gX0 = Xb + (size_t)(n0 + rb + l) * CC + kqA * 8;
  bf16* lW0 = &Wl[0][0][0] + wv * 512;
  bf16* lX0 = &Xl[0][0][0] + wv * 512;

  f32x4 acc[4][4];
  const f32x4 zero = {0.f, 0.f, 0.f, 0.f};
  #pragma unroll
  for (int i = 0; i < 4; i++)
    #pragma unroll
    for (int j = 0; j < 4; j++) acc[i][j] = zero;

  for (int k0 = 0; k0 < CC; k0 += 32){
    async16(gW0 + k0,      lW0);
    async16(gW0 + k0 + 16, lW0 + 2048);
    async16(gX0 + k0,      lX0);
    async16(gX0 + k0 + 16, lX0 + 2048);
    __syncthreads();
    bf16x8 xf[4], wf[4];
    #pragma unroll
    for (int i = 0; i < 4; i++)
      xf[i] = *(const bf16x8*)&Xl[quad][wn*64 + i*16 + l15][0];
    #pragma unroll
    for (int j = 0; j < 4; j++)
      wf[j] = *(const bf16x8*)&Wl[quad][wm*64 + j*16 + l15][0];
    #pragma unroll
    for (int i = 0; i < 4; i++)
      #pragma unroll
      for (int j = 0; j < 4; j++)
        acc[i][j] = __builtin_amdgcn_mfma_f32_16x16x32_bf16(xf[i], wf[j], acc[i][j], 0, 0, 0);
    __syncthreads();
  }

  float bb[4];
  #pragma unroll
  for (int j = 0; j < 4; j++) bb[j] = bias[m0 + wm*64 + j*16 + l15];
  #pragma unroll
  for (int i = 0; i < 4; i++){
    int nb = n0 + wn*64 + i*16 + quad*4;
    #pragma unroll
    for (int r = 0; r < 4; r++){
      float* orow = xp + ((size_t)b * HWN + nb + r) * DD;
      #pragma unroll
      for (int j = 0; j < 4; j++){
        int m = m0 + wm*64 + j*16 + l15;
        orow[m] = acc[i][j][r] + bb[j];
      }
    }
  }
}

// ---------------- K2: per-token 1/max(||x_proj||,1e-12) ----------------
__global__ __launch_bounds__(256) void k2_rnorm(const float* __restrict__ xp,
                                                float* __restrict__ rn){
  int w = threadIdx.x >> 6, l = threadIdx.x & 63;
  int t = blockIdx.x * 4 + w;               // 0..32767
  const float* row = xp + (size_t)t * DD;
  float s = 0.f;
  #pragma unroll
  for (int i = 0; i < 6; i++){ float xv = row[l + 64*i]; s += xv*xv; }
  s = wave_sum(s);
  if (l == 0) rn[t] = 1.f / fmaxf(sqrtf(s), 1e-12f);
}

// ---------------- K3: Z[b][k][n] = (clusters @ x_proj_b^T) * rnorm[n] / eps ----------
__global__ __launch_bounds__(256) void k3_scores(const float* __restrict__ clus,
                                                 const float* __restrict__ xp,
                                                 const float* __restrict__ rn,
                                                 float* __restrict__ Z){
  __shared__ float As[16][68];  // [dd][k]
  __shared__ float Bs[16][68];  // [dd][n]
  int b = blockIdx.y, n0 = blockIdx.x * 64;
  const float* xpb = xp + (size_t)b * HWN * DD;
  int tid = threadIdx.x, ty = tid >> 4, tx = tid & 15;
  float acc[4][4] = {};
  for (int d0 = 0; d0 < DD; d0 += 16){
    {
      int k = tid >> 2, q = tid & 3;
      const float4 a4 = *(const float4*)&clus[(size_t)k*DD + d0 + q*4];
      As[q*4+0][k] = a4.x; As[q*4+1][k] = a4.y; As[q*4+2][k] = a4.z; As[q*4+3][k] = a4.w;
    }
    {
      int nn = tid >> 2, q = tid & 3;
      const float4 x4 = *(const float4*)&xpb[(size_t)(n0+nn)*DD + d0 + q*4];
      Bs[q*4+0][nn] = x4.x; Bs[q*4+1][nn] = x4.y; Bs[q*4+2][nn] = x4.z; Bs[q*4+3][nn] = x4.w;
    }
    __syncthreads();
    #pragma unroll
    for (int kk = 0; kk < 16; kk++){
      const float4 a4 = *(const float4*)&As[kk][ty*4];
      const float4 b4 = *(const float4*)&Bs[kk][tx*4];
      const float av[4] = {a4.x, a4.y, a4.z, a4.w};
      const float bv[4] = {b4.x, b4.y, b4.z, b4.w};
      #pragma unroll
      for (int i = 0; i < 4; i++)
        #pragma unroll
        for (int j = 0; j < 4; j++)
          acc[i][j] = fmaf(av[i], bv[j], acc[i][j]);
    }
    __syncthreads();
  }
  const float* rnb = rn + (size_t)b * HWN;
  #pragma unroll
  for (int i = 0; i < 4; i++){
    int k = ty*4 + i;
    int n = n0 + tx*4;
    float4 o;
    o.x = acc[i][0] * rnb[n+0] * EPSI;
    o.y = acc[i][1] * rnb[n+1] * EPSI;
    o.z = acc[i][2] * rnb[n+2] * EPSI;
    o.w = acc[i][3] * rnb[n+3] * EPSI;
    *(float4*)&Z[((size_t)b*KK + k)*HWN + n] = o;
  }
}

// ---------------- K4: Sinkhorn, 8 blocks per batch, 1 device barrier per iter -------
// Shift trick: u_new = u_prev - log(sum_n exp(Z + v + u_prev - NORMC))
//              v_new = v_prev - log(sum_m exp(Z + u_new + v_prev - NORMC))
// (mathematically exact logsumexp; args <= 0 after iter 0, <= 27 at iter 0;
//  no global max reductions needed -> only the u-partial sum crosses blocks)
__global__ __launch_bounds__(256) void k4_sinkhorn(const float* __restrict__ Z,
                                                   float* __restrict__ U,
                                                   float* __restrict__ V,
                                                   float* __restrict__ part,
                                                   unsigned* __restrict__ cnt){
  __shared__ float Zs[64][128];   // this block's column slice (32 KB)
  __shared__ float v_l[128];
  __shared__ float u_l[64];
  __shared__ float spart[256];
  int bg = blockIdx.x;
  int b = bg >> 3, g = bg & 7;
  int n0 = g * 128;
  const float* Zb = Z + (size_t)b * KK * HWN;
  int t = threadIdx.x, w = t >> 6, l = t & 63;

  // stage Z slice into LDS (rows 64 x owned cols 128)
  #pragma unroll
  for (int ch = 0; ch < 8; ch++){
    int i = ch*1024 + t*4;        // linear over [64][128]
    int r = i >> 7, c = i & 127;
    float4 zv = *(const float4*)&Zb[(size_t)r*HWN + n0 + c];
    *(float4*)&Zs[r][c] = zv;
  }
  if (t < 128) v_l[t] = 0.f;
  if (t < 64)  u_l[t] = 0.f;
  __syncthreads();

  for (int it = 0; it < NITERS; it++){
    float* pp = part + (it & 1) * (32*64*8);   // double-buffered partials
    // ---- u partials over owned 128 cols; wave w owns rows 16w..16w+15
    float ev0 = v_l[l]      - NORMC;
    float ev1 = v_l[l + 64] - NORMC;
    #pragma unroll
    for (int rr = 0; rr < 16; rr++){
      int r = w*16 + rr;
      float ur = u_l[r];
      float e = __expf(Zs[r][l] + ev0 + ur) + __expf(Zs[r][l+64] + ev1 + ur);
      e = wave_sum(e);
      if (l == 0) pp[((size_t)b*64 + r)*8 + g] = e;
    }
    batch_barrier(&cnt[b*16 + it]);
    // ---- u reduce (replicated in every block)
    if (t < 64){
      const float4* p4 = (const float4*)&pp[((size_t)b*64 + t)*8];
      float4 a = p4[0], bq = p4[1];
      float s = ((a.x + a.y) + (a.z + a.w)) + ((bq.x + bq.y) + (bq.z + bq.w));
      u_l[t] = u_l[t] - __logf(s);
    }
    __syncthreads();
    // ---- v phase: thread t -> col c = t&127, row half h = t>>7
    {
      int c = t & 127, h = t >> 7;
      float vc = v_l[c] - NORMC;
      float s = 0.f;
      #pragma unroll
      for (int m = 0; m < 32; m++){
        int r = h*32 + m;
        s += __expf(Zs[r][c] + u_l[r] + vc);
      }
      spart[t] = s;
    }
    __syncthreads();
    if (t < 128) v_l[t] = v_l[t] - __logf(spart[t] + spart[t + 128]);
    __syncthreads();
  }
  if (t < 128) V[b*HWN + n0 + t] = v_l[t];
  if (g == 0 && t < 64) U[b*KK + t] = u_l[t];
}

// ---------------- K5: v_tilde[b][k][d] = sum_n exp(Z+u+v-norm) * xp[n][d]*rnorm[n] ----
__global__ __launch_bounds__(256) void k5_vtilde(const float* __restrict__ Z,
                                                 const float* __restrict__ U,
                                                 const float* __restrict__ V,
                                                 const float* __restrict__ xp,
                                                 const float* __restrict__ rn,
                                                 float* __restrict__ out){
  __shared__ float As[16][68];
  __shared__ float Bs[16][64];
  int b = blockIdx.y;
  int d0 = blockIdx.x * 64;
  const float* Zb  = Z + (size_t)b * KK * HWN;
  const float* ub  = U + (size_t)b * KK;
  const float* vb  = V + (size_t)b * HWN;
  const float* xpb = xp + (size_t)b * HWN * DD;
  const float* rnb = rn + (size_t)b * HWN;
  int tid = threadIdx.x, ty = tid >> 4, tx = tid & 15;
  float acc[4][4] = {};
  for (int n0 = 0; n0 < HWN; n0 += 16){
    {
      int m = tid >> 2, q = tid & 3;
      float um = ub[m];
      const float4 z4 = *(const float4*)&Zb[(size_t)m*HWN + n0 + q*4];
      const float4 v4 = *(const float4*)&vb[n0 + q*4];
      As[q*4+0][m] = __expf(z4.x + um + v4.x - NORMC);
      As[q*4+1][m] = __expf(z4.y + um + v4.y - NORMC);
      As[q*4+2][m] = __expf(z4.z + um + v4.z - NORMC);
      As[q*4+3][m] = __expf(z4.w + um + v4.w - NORMC);
    }
    {
      int r = tid >> 4, cd = (tid & 15) * 4;
      float sc = rnb[n0 + r];
      float4 xv = *(const float4*)&xpb[(size_t)(n0+r)*DD + d0 + cd];
      xv.x *= sc; xv.y *= sc; xv.z *= sc; xv.w *= sc;
      *(float4*)&Bs[r][cd] = xv;
    }
    __syncthreads();
    #pragma unroll
    for (int kk = 0; kk < 16; kk++){
      const float4 a4 = *(const float4*)&As[kk][ty*4];
      const float4 b4 = *(const float4*)&Bs[kk][tx*4];
      const float av[4] = {a4.x, a4.y, a4.z, a4.w};
      const float bv[4] = {b4.x, b4.y, b4.z, b4.w};
      #pragma unroll
      for (int i = 0; i < 4; i++)
        #pragma unroll
        for (int j = 0; j < 4; j++)
          acc[i][j] = fmaf(av[i], bv[j], acc[i][j]);
    }
    __syncthreads();
  }
  #pragma unroll
  for (int i = 0; i < 4; i++){
    int k = ty*4 + i;
    float4 o; o.x = acc[i][0]; o.y = acc[i][1]; o.z = acc[i][2]; o.w = acc[i][3];
    *(float4*)&out[((size_t)b*KK + k)*DD + d0 + tx*4] = o;
  }
}

extern "C" void kernel_launch(void* const* d_in, const int* in_sizes, int n_in,
                              void* d_out, int out_size, void* d_ws, size_t ws_size,
                              hipStream_t stream) {
  const float* x      = (const float*)d_in[0];   // [32,768,32,32]
  const float* conv_w = (const float*)d_in[1];   // [384,768]
  const float* conv_b = (const float*)d_in[2];   // [384]
  const float* vcode  = (const float*)d_in[3];   // [64,384]
  float* out = (float*)d_out;
  float* vt_out = out;                 // [32,64,384]  = 786432
  float* xp_out = out + 786432;        // [32,1024,384]

  bf16* Xt   = (bf16*)d_ws;                          // 25165824 elems (50.3 MB)
  bf16* Wb   = Xt + (size_t)BB * HWN * CC;           // 294912 elems (0.6 MB)
  float* clus = (float*)(Wb + (size_t)DD * CC);      // 24576
  float* Zbuf = clus + 24576;                        // 2097152
  float* Ubuf = Zbuf + 2097152;                      // 2048
  float* Vbuf = Ubuf + 2048;                         // 32768
  float* Rn   = Vbuf + 32768;                        // 32768
  float* Part = Rn + 32768;                          // 32768 (2x16384, dbuf partials)
  unsigned* Cnt = (unsigned*)(Part + 32768);         // 512 barrier counters

  k_init<<<1, 512, 0, stream>>>(Cnt);
  k0_clusters<<<16, 256, 0, stream>>>(vcode, clus);
  k_wconv<<<288, 256, 0, stream>>>(conv_w, Wb);
  k_xt<<<dim3(16, 12, 32), 256, 0, stream>>>(x, Xt);
  k_gemm<<<dim3(8, 3, 32), 256, 0, stream>>>(Wb, Xt, conv_b, xp_out);
  k2_rnorm<<<8192, 256, 0, stream>>>(xp_out, Rn);
  k3_scores<<<dim3(16, 32), 256, 0, stream>>>(clus, xp_out, Rn, Zbuf);
  k4_sinkhorn<<<256, 256, 0, stream>>>(Zbuf, Ubuf, Vbuf, Part, Cnt);
  k5_vtilde<<<dim3(6, 32), 256, 0, stream>>>(Zbuf, Ubuf, Vbuf, xp_out, Rn, vt_out);
}

// Round 5
// 357.889 us; speedup vs baseline: 1.7814x; 1.1887x over previous
//
#include <hip/hip_runtime.h>
#include <math.h>

#define BB 32
#define CC 768
#define HWN 1024
#define DD 384
#define KK 64
#define EPSI 20.0f            // 1/eps
#define NORMC (-6.9920964f)   // -log(1088)
#define NITERS 10

typedef __bf16 bf16;
typedef bf16 bf16x8 __attribute__((ext_vector_type(8)));
typedef bf16 bf16x4 __attribute__((ext_vector_type(4)));
typedef float f32x4 __attribute__((ext_vector_type(4)));
typedef _Float16 f16;
typedef f16 f16x2 __attribute__((ext_vector_type(2)));
typedef f16 f16x4 __attribute__((ext_vector_type(4)));

__device__ __forceinline__ float wave_sum(float v){
  #pragma unroll
  for (int off = 32; off; off >>= 1) v += __shfl_xor(v, off, 64);
  return v;
}
__device__ __forceinline__ float wave_max(float v){
  #pragma unroll
  for (int off = 32; off; off >>= 1) v = fmaxf(v, __shfl_xor(v, off, 64));
  return v;
}

__device__ __forceinline__ void async16(const bf16* g, bf16* l){
  __builtin_amdgcn_global_load_lds((const __attribute__((address_space(1))) unsigned int*)g,
                                   (__attribute__((address_space(3))) unsigned int*)l,
                                   16, 0, 0);
}

// ---------------- K0: normalize codebook rows v[64][384] -> clusters ----------------
__global__ __launch_bounds__(256) void k0_clusters(const float* __restrict__ vin,
                                                   float* __restrict__ clus){
  int w = threadIdx.x >> 6, l = threadIdx.x & 63;
  int k = blockIdx.x * 4 + w;               // 16 blocks * 4 waves = 64 rows
  float s = 0.f;
  #pragma unroll
  for (int i = 0; i < 6; i++){ float x = vin[k*DD + l + 64*i]; s += x*x; }
  s = wave_sum(s);
  float scale = 1.f / fmaxf(sqrtf(s), 1e-12f);
  #pragma unroll
  for (int i = 0; i < 6; i++) clus[k*DD + l + 64*i] = vin[k*DD + l + 64*i] * scale;
}

// ---------------- KW: convert conv_w fp32[384][768] -> bf16 ----------------
__global__ __launch_bounds__(256) void k_wconv(const float* __restrict__ w,
                                               bf16* __restrict__ wb){
  int i = (blockIdx.x * 256 + threadIdx.x) * 4;
  float4 v = *(const float4*)&w[i];
  bf16x4 o;
  o[0] = (bf16)v.x; o[1] = (bf16)v.y; o[2] = (bf16)v.z; o[3] = (bf16)v.w;
  *(bf16x4*)&wb[i] = o;
}

// ---------------- KXT: X[b][768][1024] fp32 -> Xt[b][1024][768] bf16 (transpose) -----
__global__ __launch_bounds__(256) void k_xt(const float* __restrict__ x,
                                            bf16* __restrict__ xt){
  __shared__ float S[64][68];
  int b  = blockIdx.z;
  int k0 = blockIdx.y * 64;   // channel dim
  int n0 = blockIdx.x * 64;   // spatial dim
  const float* X = x + (size_t)b * CC * HWN;
  int t = threadIdx.x;
  int rr = t >> 4, cc = (t & 15) * 4;
  #pragma unroll
  for (int it = 0; it < 4; it++){
    float4 v = *(const float4*)&X[(size_t)(k0 + rr + it*16)*HWN + n0 + cc];
    *(float4*)&S[rr + it*16][cc] = v;
  }
  __syncthreads();
  int n = t >> 2, kc = t & 3;
  bf16* orow = xt + (size_t)b * HWN * CC + (size_t)(n0 + n) * CC + k0;
  #pragma unroll
  for (int half = 0; half < 2; half++){
    int kb = half*32 + kc*8;
    bf16x8 o;
    #pragma unroll
    for (int jj = 0; jj < 8; jj++){
      int j = (jj + kc) & 7;   // rotate read order to dodge bank conflicts
      o[j] = (bf16)S[kb + j][n];
    }
    *(bf16x8*)&orow[kb] = o;
  }
}

// ---------------- K1: MFMA GEMM  xp[b][n][m] = sum_k Xt[b][n][k] * Wb[m][k] + bias[m]
__global__ __launch_bounds__(256) void k_gemm(const bf16* __restrict__ Wb,
                                              const bf16* __restrict__ Xt,
                                              const float* __restrict__ bias,
                                              float* __restrict__ xp){
  __shared__ bf16 Wl[4][128][8];   // [kquad][row(m)][8 bf16]  8 KB
  __shared__ bf16 Xl[4][128][8];   // [kquad][row(n)][8 bf16]  8 KB
  int b  = blockIdx.z;
  int m0 = blockIdx.y * 128;
  int n0 = blockIdx.x * 128;
  int t = threadIdx.x, wv = t >> 6, l = t & 63;
  int l15 = l & 15, quad = l >> 4;
  int wn = wv >> 1, wm = wv & 1;
  const bf16* Xb = Xt + (size_t)b * HWN * CC;

  int kqA = wv >> 1;
  int rb  = (wv & 1) * 64;
  const bf16* gW0 = Wb + (size_t)(m0 + rb + l) * CC + kqA * 8;
  const bf16* gX0 = Xb + (size_t)(n0 + rb + l) * CC + kqA * 8;
  bf16* lW0 = &Wl[0][0][0] + wv * 512;
  bf16* lX0 = &Xl[0][0][0] + wv * 512;

  f32x4 acc[4][4];
  const f32x4 zero = {0.f, 0.f, 0.f, 0.f};
  #pragma unroll
  for (int i = 0; i < 4; i++)
    #pragma unroll
    for (int j = 0; j < 4; j++) acc[i][j] = zero;

  for (int k0 = 0; k0 < CC; k0 += 32){
    async16(gW0 + k0,      lW0);
    async16(gW0 + k0 + 16, lW0 + 2048);
    async16(gX0 + k0,      lX0);
    async16(gX0 + k0 + 16, lX0 + 2048);
    __syncthreads();
    bf16x8 xf[4], wf[4];
    #pragma unroll
    for (int i = 0; i < 4; i++)
      xf[i] = *(const bf16x8*)&Xl[quad][wn*64 + i*16 + l15][0];
    #pragma unroll
    for (int j = 0; j < 4; j++)
      wf[j] = *(const bf16x8*)&Wl[quad][wm*64 + j*16 + l15][0];
    #pragma unroll
    for (int i = 0; i < 4; i++)
      #pragma unroll
      for (int j = 0; j < 4; j++)
        acc[i][j] = __builtin_amdgcn_mfma_f32_16x16x32_bf16(xf[i], wf[j], acc[i][j], 0, 0, 0);
    __syncthreads();
  }

  float bb[4];
  #pragma unroll
  for (int j = 0; j < 4; j++) bb[j] = bias[m0 + wm*64 + j*16 + l15];
  #pragma unroll
  for (int i = 0; i < 4; i++){
    int nb = n0 + wn*64 + i*16 + quad*4;
    #pragma unroll
    for (int r = 0; r < 4; r++){
      float* orow = xp + ((size_t)b * HWN + nb + r) * DD;
      #pragma unroll
      for (int j = 0; j < 4; j++){
        int m = m0 + wm*64 + j*16 + l15;
        orow[m] = acc[i][j][r] + bb[j];
      }
    }
  }
}

// ---------------- K2: per-token 1/max(||x_proj||,1e-12) ----------------
__global__ __launch_bounds__(256) void k2_rnorm(const float* __restrict__ xp,
                                                float* __restrict__ rn){
  int w = threadIdx.x >> 6, l = threadIdx.x & 63;
  int t = blockIdx.x * 4 + w;               // 0..32767
  const float* row = xp + (size_t)t * DD;
  float s = 0.f;
  #pragma unroll
  for (int i = 0; i < 6; i++){ float xv = row[l + 64*i]; s += xv*xv; }
  s = wave_sum(s);
  if (l == 0) rn[t] = 1.f / fmaxf(sqrtf(s), 1e-12f);
}

// ---------------- K3: Z[b][k][n] = (clusters @ x_proj_b^T) * rnorm[n] / eps ----------
__global__ __launch_bounds__(256) void k3_scores(const float* __restrict__ clus,
                                                 const float* __restrict__ xp,
                                                 const float* __restrict__ rn,
                                                 float* __restrict__ Z){
  __shared__ float As[16][68];  // [dd][k]
  __shared__ float Bs[16][68];  // [dd][n]
  int b = blockIdx.y, n0 = blockIdx.x * 64;
  const float* xpb = xp + (size_t)b * HWN * DD;
  int tid = threadIdx.x, ty = tid >> 4, tx = tid & 15;
  float acc[4][4] = {};
  for (int d0 = 0; d0 < DD; d0 += 16){
    {
      int k = tid >> 2, q = tid & 3;
      const float4 a4 = *(const float4*)&clus[(size_t)k*DD + d0 + q*4];
      As[q*4+0][k] = a4.x; As[q*4+1][k] = a4.y; As[q*4+2][k] = a4.z; As[q*4+3][k] = a4.w;
    }
    {
      int nn = tid >> 2, q = tid & 3;
      const float4 x4 = *(const float4*)&xpb[(size_t)(n0+nn)*DD + d0 + q*4];
      Bs[q*4+0][nn] = x4.x; Bs[q*4+1][nn] = x4.y; Bs[q*4+2][nn] = x4.z; Bs[q*4+3][nn] = x4.w;
    }
    __syncthreads();
    #pragma unroll
    for (int kk = 0; kk < 16; kk++){
      const float4 a4 = *(const float4*)&As[kk][ty*4];
      const float4 b4 = *(const float4*)&Bs[kk][tx*4];
      const float av[4] = {a4.x, a4.y, a4.z, a4.w};
      const float bv[4] = {b4.x, b4.y, b4.z, b4.w};
      #pragma unroll
      for (int i = 0; i < 4; i++)
        #pragma unroll
        for (int j = 0; j < 4; j++)
          acc[i][j] = fmaf(av[i], bv[j], acc[i][j]);
    }
    __syncthreads();
  }
  const float* rnb = rn + (size_t)b * HWN;
  #pragma unroll
  for (int i = 0; i < 4; i++){
    int k = ty*4 + i;
    int n = n0 + tx*4;
    float4 o;
    o.x = acc[i][0] * rnb[n+0] * EPSI;
    o.y = acc[i][1] * rnb[n+1] * EPSI;
    o.z = acc[i][2] * rnb[n+2] * EPSI;
    o.w = acc[i][3] * rnb[n+3] * EPSI;
    *(float4*)&Z[((size_t)b*KK + k)*HWN + n] = o;
  }
}

// ---------------- K4: Sinkhorn, one 1024-thr block per batch, E=exp(Z-rmax) in f16 LDS
// u[r] = NORMC - rmax[r] - log(sum_n E[r][n]*ev[n]);  eu[r] = exp(NORMC)/sum  (exact)
// v[c] = NORMC - log(sum_m E[m][c]*eu[m]);            ev[c] = exp(v[c])
// NOTE: v reaches ~+12 here (asymmetric marginals 64 vs 1024), so ev MUST be fp32 —
// f16 ev (max 65504 = e^11.09) overflowed to Inf in R3 and cascaded to NaN.
// E in (0,1] is always f16-safe. ~145 KB LDS (gfx950: 160 KB/CU).
__global__ __launch_bounds__(1024) void k4_sinkhorn(const float* __restrict__ Z,
                                                    float* __restrict__ U,
                                                    float* __restrict__ V){
  __shared__ f16  E[64][1024];    // 128 KB
  __shared__ float evf[1024];     // exp(v), fp32 (overflow-safe)
  __shared__ float eu[64];
  __shared__ float rmax[64];
  __shared__ float u_l[64];
  __shared__ float v_l[1024];
  __shared__ float sp[2][1024];   // v-phase partials per column (two row-halves)
  int b = blockIdx.x;
  const float* Zb = Z + (size_t)b * KK * HWN;
  int t = threadIdx.x, w = t >> 6, l = t & 63;

  // ---- stage: wave w owns rows 4w..4w+3; compute rowmax, E = f16(exp(Z - rmax))
  #pragma unroll
  for (int rr = 0; rr < 4; rr++){
    int r = w*4 + rr;
    float4 z[4];
    float mx = -INFINITY;
    #pragma unroll
    for (int j = 0; j < 4; j++){
      z[j] = *(const float4*)&Zb[(size_t)r*HWN + 4*l + 256*j];
      mx = fmaxf(mx, fmaxf(fmaxf(z[j].x, z[j].y), fmaxf(z[j].z, z[j].w)));
    }
    mx = wave_max(mx);
    if (l == 0) rmax[r] = mx;
    #pragma unroll
    for (int j = 0; j < 4; j++){
      f16x4 e4;
      e4[0] = (f16)__expf(z[j].x - mx); e4[1] = (f16)__expf(z[j].y - mx);
      e4[2] = (f16)__expf(z[j].z - mx); e4[3] = (f16)__expf(z[j].w - mx);
      *(f16x4*)&E[r][4*l + 256*j] = e4;
    }
  }
  evf[t] = 1.f;
  v_l[t] = 0.f;
  __syncthreads();

  for (int it = 0; it < NITERS; it++){
    // ---- u-phase: wave w -> rows 4w..4w+3; lane l covers col-pairs p = l+64j
    float evx[16];
    #pragma unroll
    for (int j = 0; j < 8; j++){
      float2 e2 = *(const float2*)&evf[2*(l + 64*j)];
      evx[2*j] = e2.x; evx[2*j+1] = e2.y;
    }
    float us[4];
    #pragma unroll
    for (int rr = 0; rr < 4; rr++){
      int r = w*4 + rr;
      float s = 0.f;
      #pragma unroll
      for (int j = 0; j < 8; j++){
        f16x2 e2 = *(const f16x2*)&E[r][2*(l + 64*j)];
        s = fmaf((float)e2[0], evx[2*j],   s);
        s = fmaf((float)e2[1], evx[2*j+1], s);
      }
      us[rr] = wave_sum(s);
    }
    if (l == 0){
      #pragma unroll
      for (int rr = 0; rr < 4; rr++){
        int r = w*4 + rr;
        u_l[r] = NORMC - rmax[r] - __logf(us[rr]);
        eu[r]  = __expf(NORMC) / us[rr];      // = exp(u+rmax), no transcendental
      }
    }
    __syncthreads();
    // ---- v-phase: thread t -> col pair p = t&511, row half h = t>>9
    {
      int p = t & 511, h = t >> 9;
      float sx = 0.f, sy = 0.f;
      #pragma unroll
      for (int mq = 0; mq < 8; mq++){
        float4 eu4 = *(const float4*)&eu[h*32 + mq*4];
        const float euv[4] = {eu4.x, eu4.y, eu4.z, eu4.w};
        #pragma unroll
        for (int i = 0; i < 4; i++){
          f16x2 e2 = *(const f16x2*)&E[h*32 + mq*4 + i][2*p];
          sx = fmaf((float)e2[0], euv[i], sx);
          sy = fmaf((float)e2[1], euv[i], sy);
        }
      }
      float2 o; o.x = sx; o.y = sy;
      *(float2*)&sp[h][2*p] = o;
    }
    __syncthreads();
    if (t < 512){
      int p = t;
      float2 a = *(const float2*)&sp[0][2*p];
      float2 c = *(const float2*)&sp[1][2*p];
      float vx = NORMC - __logf(a.x + c.x);
      float vy = NORMC - __logf(a.y + c.y);
      v_l[2*p]   = vx;
      v_l[2*p+1] = vy;
      float2 ee; ee.x = __expf(vx); ee.y = __expf(vy);
      *(float2*)&evf[2*p] = ee;
    }
    __syncthreads();
  }
  V[b*HWN + t] = v_l[t];
  if (t < 64) U[b*KK + t] = u_l[t];
}

// ---------------- K5: v_tilde[b][k][d] = sum_n exp(Z+u+v-norm) * xp[n][d]*rnorm[n] ----
__global__ __launch_bounds__(256) void k5_vtilde(const float* __restrict__ Z,
                                                 const float* __restrict__ U,
                                                 const float* __restrict__ V,
                                                 const float* __restrict__ xp,
                                                 const float* __restrict__ rn,
                                                 float* __restrict__ out){
  __shared__ float As[16][68];
  __shared__ float Bs[16][64];
  int b = blockIdx.y;
  int d0 = blockIdx.x * 64;
  const float* Zb  = Z + (size_t)b * KK * HWN;
  const float* ub  = U + (size_t)b * KK;
  const float* vb  = V + (size_t)b * HWN;
  const float* xpb = xp + (size_t)b * HWN * DD;
  const float* rnb = rn + (size_t)b * HWN;
  int tid = threadIdx.x, ty = tid >> 4, tx = tid & 15;
  float acc[4][4] = {};
  for (int n0 = 0; n0 < HWN; n0 += 16){
    {
      int m = tid >> 2, q = tid & 3;
      float um = ub[m];
      const float4 z4 = *(const float4*)&Zb[(size_t)m*HWN + n0 + q*4];
      const float4 v4 = *(const float4*)&vb[n0 + q*4];
      As[q*4+0][m] = __expf(z4.x + um + v4.x - NORMC);
      As[q*4+1][m] = __expf(z4.y + um + v4.y - NORMC);
      As[q*4+2][m] = __expf(z4.z + um + v4.z - NORMC);
      As[q*4+3][m] = __expf(z4.w + um + v4.w - NORMC);
    }
    {
      int r = tid >> 4, cd = (tid & 15) * 4;
      float sc = rnb[n0 + r];
      float4 xv = *(const float4*)&xpb[(size_t)(n0+r)*DD + d0 + cd];
      xv.x *= sc; xv.y *= sc; xv.z *= sc; xv.w *= sc;
      *(float4*)&Bs[r][cd] = xv;
    }
    __syncthreads();
    #pragma unroll
    for (int kk = 0; kk < 16; kk++){
      const float4 a4 = *(const float4*)&As[kk][ty*4];
      const float4 b4 = *(const float4*)&Bs[kk][tx*4];
      const float av[4] = {a4.x, a4.y, a4.z, a4.w};
      const float bv[4] = {b4.x, b4.y, b4.z, b4.w};
      #pragma unroll
      for (int i = 0; i < 4; i++)
        #pragma unroll
        for (int j = 0; j < 4; j++)
          acc[i][j] = fmaf(av[i], bv[j], acc[i][j]);
    }
    __syncthreads();
  }
  #pragma unroll
  for (int i = 0; i < 4; i++){
    int k = ty*4 + i;
    float4 o; o.x = acc[i][0]; o.y = acc[i][1]; o.z = acc[i][2]; o.w = acc[i][3];
    *(float4*)&out[((size_t)b*KK + k)*DD + d0 + tx*4] = o;
  }
}

extern "C" void kernel_launch(void* const* d_in, const int* in_sizes, int n_in,
                              void* d_out, int out_size, void* d_ws, size_t ws_size,
                              hipStream_t stream) {
  const float* x      = (const float*)d_in[0];   // [32,768,32,32]
  const float* conv_w = (const float*)d_in[1];   // [384,768]
  const float* conv_b = (const float*)d_in[2];   // [384]
  const float* vcode  = (const float*)d_in[3];   // [64,384]
  float* out = (float*)d_out;
  float* vt_out = out;                 // [32,64,384]  = 786432
  float* xp_out = out + 786432;        // [32,1024,384]

  bf16* Xt   = (bf16*)d_ws;                          // 25165824 elems (50.3 MB)
  bf16* Wb   = Xt + (size_t)BB * HWN * CC;           // 294912 elems (0.6 MB)
  float* clus = (float*)(Wb + (size_t)DD * CC);      // 24576
  float* Zbuf = clus + 24576;                        // 2097152
  float* Ubuf = Zbuf + 2097152;                      // 2048
  float* Vbuf = Ubuf + 2048;                         // 32768
  float* Rn   = Vbuf + 32768;                        // 32768

  k0_clusters<<<16, 256, 0, stream>>>(vcode, clus);
  k_wconv<<<288, 256, 0, stream>>>(conv_w, Wb);
  k_xt<<<dim3(16, 12, 32), 256, 0, stream>>>(x, Xt);
  k_gemm<<<dim3(8, 3, 32), 256, 0, stream>>>(Wb, Xt, conv_b, xp_out);
  k2_rnorm<<<8192, 256, 0, stream>>>(xp_out, Rn);
  k3_scores<<<dim3(16, 32), 256, 0, stream>>>(clus, xp_out, Rn, Zbuf);
  k4_sinkhorn<<<32, 1024, 0, stream>>>(Zbuf, Ubuf, Vbuf);
  k5_vtilde<<<dim3(6, 32), 256, 0, stream>>>(Zbuf, Ubuf, Vbuf, xp_out, Rn, vt_out);
}